// Round 9
// baseline (294.657 us; speedup 1.0000x reference)
//
#include <hip/hip_runtime.h>

// Problem constants
#define NB 128
#define NC 256
#define HX 31
#define WX 31
#define HC 25          // corr spatial (31-7+1)
#define WC 25
#define HO 23          // head output spatial (25-3+1)
#define WO 23
#define CHUNKS 8       // channel chunks per batch item -> 1024 blocks (atomics halved vs 2048)
#define CPB (NC / CHUNKS)    // 32 channels per block
#define GRP 10               // 25 thr/ch -> 250/256 lanes; groups 10,10,10,2 = 13 corr wave-streams
#define ZCH 56               // z: 7 rows * 8 stride (16B-aligned rows)
#define WCH 48               // weights: 45 padded to 48 (12 float4)
#define CCH (HC * WC)        // 625

#define NPIX (HO * WO)               // 529
#define HEAT_SZ (NB * NPIX)          // 67712
#define REG_SZ  (NB * 4 * NPIX)      // 270848
#define OUT_TOTAL (HEAT_SZ + REG_SZ) // 338560
#define NSTRIP3 (HO * 8)             // 184 three-pixel strips (last in row = 2)

// unaligned-capable float4 (x rows / cs rows start at arbitrary dword offsets)
typedef float f4v __attribute__((ext_vector_type(4), aligned(4)));

// Writes bias into d_out (harness poisons d_out before every launch).
__global__ void init_out_kernel(float* __restrict__ out,
                                const float* __restrict__ heat_b,
                                const float* __restrict__ reg_b) {
    int i = blockIdx.x * 256 + threadIdx.x;
    if (i >= OUT_TOTAL) return;
    if (i < HEAT_SZ) {
        out[i] = heat_b[0];
    } else {
        int j = i - HEAT_SZ;
        int o = (j / NPIX) & 3;
        out[i] = reg_b[o];
    }
}

// Fused exact-corr + head kernel, v9 (measured-best composition):
//  - CHUNKS=8/CPB=32/GRP=10: v3's grouping. 25 thr/ch corr -> GRP=10 is the
//    wave-packing optimum (250/256 lanes); 10,10,10,2 = 13 corr wave-streams
//    vs 16 for even-8 (exec-masked lanes still pay full-wave issue).
//    1024 blocks halves atomic count vs CHUNKS=16 (WRITE 84->~50MB measured).
//  - strip head from v6: 184 threads x 3-pixel strips, 6 LDS reads per
//    channel-strip; wave 3 exec-skips (idle, but no issue cost).
//  - z-prefetch (T14 issue-early/write-late): next group's z global loads
//    issued before the corr->head barrier (regs, +2 VGPR), ds_write after
//    head, zs double-buffered -> z-stage latency hidden under head FMA.
//  - workspace path dropped: counters proved d_ws never provided (WRITE
//    84/133MB = atomic scale across v6/v7). Atomic epilogue + init kernel.
__launch_bounds__(256, 4)
__global__ void fused_head_kernel(const float* __restrict__ xf,
                                  const float* __restrict__ zf,
                                  const float* __restrict__ hw,
                                  const float* __restrict__ rw,
                                  float* __restrict__ out) {
    __shared__ __align__(16) float cs[GRP * CCH + 8];   // 25.0 KB (+pad: tail-strip overread)
    __shared__ __align__(16) float zs[2][GRP * ZCH];    // 4.5 KB (double-buffered)
    __shared__ __align__(16) float ws[CPB * WCH];       // 6.0 KB

    const int tid = threadIdx.x;
    const int n = blockIdx.x >> 3;
    const int chunk = blockIdx.x & 7;
    const int cbase = chunk * CPB;

    // corr mapping: 25 threads/channel, each owns an exact 5x5 corr tile
    const int cl = tid / 25;               // channel-in-group (>=G -> idle)
    const int tt = tid % 25;
    const int tr = tt / 5, tc = tt % 5;
    const int i0 = tr * 5, j0 = tc * 5;

    // head mapping: 3-pixel strips. strip sid -> row sid/8, cols 3*(sid%8)..+2
    const bool hasS = (tid < NSTRIP3);     // threads 184..255 exec-skip head
    const int sy = tid >> 3;               // 0..22
    const int sx = tid & 7;                // 0..7
    const int cx = sx * 3;                 // 0,3,...,21
    const int offS = sy * WC + cx;

    float accH[3] = {0.f, 0.f, 0.f};
    float accR[4][3] = {{0.f,0.f,0.f},{0.f,0.f,0.f},{0.f,0.f,0.f},{0.f,0.f,0.f}};

    const float* xn = xf + ((size_t)n * NC + cbase) * (HX * WX);
    const float* zn = zf + ((size_t)n * NC + cbase) * 49;

    // ---- stage all 32 channels' head weights once (v3 layout) ----
    for (int idx = tid; idx < CPB * 45; idx += 256) {
        int ch = idx / 45, j = idx - ch * 45;
        int c = cbase + ch;
        float v;
        if (j < 9) {
            v = hw[c * 9 + j];
        } else {
            int o = (j - 9) / 9;
            int jj = (j - 9) - o * 9;
            v = rw[((size_t)o * NC + c) * 9 + jj];
        }
        ws[ch * WCH + j] = v;
    }

    // ---- prologue: stage z for group 0 (G=10, 490 contiguous floats) ----
    for (int idx = tid; idx < GRP * 49; idx += 256) {
        int ch = idx / 49, q = idx - ch * 49;
        int u = q / 7, v = q - u * 7;
        zs[0][ch * ZCH + u * 8 + v] = zn[idx];
    }
    __syncthreads();

    int gi = 0;
    for (int g0 = 0; g0 < CPB; g0 += GRP, ++gi) {
        const int G = (CPB - g0) < GRP ? (CPB - g0) : GRP;   // 10,10,10,2
        const float* zsb = zs[gi & 1];

        // ---- exact corr: x from global, 1-row lookahead (v6-proven body) ----
        if (cl < G) {
            const float* xb = xn + (size_t)(g0 + cl) * (HX * WX) + i0 * WX + j0;
            const float* zb = zsb + cl * ZCH;

            float cacc[5][5];
            #pragma unroll
            for (int r = 0; r < 5; ++r)
                #pragma unroll
                for (int b = 0; b < 5; ++b) cacc[r][b] = 0.f;

            f4v c0 = *(const f4v*)(xb);
            f4v c1 = *(const f4v*)(xb + 4);
            f4v c2 = *(const f4v*)(xb + 7);   // cols j0+7..j0+10 (max col 30)

            #pragma unroll
            for (int rl = 0; rl < 11; ++rl) {
                f4v n0, n1, n2;
                if (rl < 10) {
                    const float* rp = xb + (rl + 1) * WX;
                    n0 = *(const f4v*)(rp);
                    n1 = *(const f4v*)(rp + 4);
                    n2 = *(const f4v*)(rp + 7);
                }
                const float xr[11] = {c0.x, c0.y, c0.z, c0.w,
                                      c1.x, c1.y, c1.z, c1.w,
                                      c2.y, c2.z, c2.w};
                #pragma unroll
                for (int u = 0; u < 7; ++u) {
                    const int r = rl - u;           // folds at compile time
                    if (r >= 0 && r < 5) {
                        f4v za = *(const f4v*)(zb + u * 8);      // broadcast
                        f4v zc = *(const f4v*)(zb + u * 8 + 4);
                        const float zz[7] = {za.x, za.y, za.z, za.w,
                                             zc.x, zc.y, zc.z};
                        #pragma unroll
                        for (int v = 0; v < 7; ++v)
                            #pragma unroll
                            for (int b = 0; b < 5; ++b)
                                cacc[r][b] = fmaf(zz[v], xr[b + v], cacc[r][b]);
                    }
                }
                if (rl < 10) { c0 = n0; c1 = n1; c2 = n2; }
            }
            float* cb = cs + cl * CCH + i0 * WC + j0;
            #pragma unroll
            for (int r = 0; r < 5; ++r)
                #pragma unroll
                for (int b = 0; b < 5; ++b) cb[r * WC + b] = cacc[r][b];
        }

        // ---- issue next group's z loads EARLY (regs; latency hides under head) ----
        const int g1 = g0 + GRP;
        const bool pf = (g1 < CPB);
        const int cnt = pf ? ((CPB - g1) < GRP ? (CPB - g1) : GRP) * 49 : 0;
        float zr0 = 0.f, zr1 = 0.f;
        if (tid < cnt)       zr0 = zn[(size_t)g1 * 49 + tid];
        if (tid + 256 < cnt) zr1 = zn[(size_t)g1 * 49 + tid + 256];

        __syncthreads();   // A: cs ready for head

        // ---- conv heads: 3-pixel strips, w[48] broadcast tile ----
        if (hasS) {
            for (int clc = 0; clc < G; ++clc) {
                float w[48];
                {
                    const f4v* wp = (const f4v*)(ws + (size_t)(g0 + clc) * WCH);
                    #pragma unroll
                    for (int q = 0; q < 12; ++q) {     // broadcast b128
                        f4v t = wp[q];
                        w[q * 4 + 0] = t.x; w[q * 4 + 1] = t.y;
                        w[q * 4 + 2] = t.z; w[q * 4 + 3] = t.w;
                    }
                }
                const float* base = cs + clc * CCH + offS;

                #pragma unroll
                for (int dy = 0; dy < 3; ++dy) {
                    f4v f = *(const f4v*)(base + dy * WC);   // cols cx..cx+3
                    const float f4 = base[dy * WC + 4];      // col cx+4
                    #pragma unroll
                    for (int dx = 0; dx < 3; ++dx) {
                        const int k = dy * 3 + dx;
                        #pragma unroll
                        for (int px = 0; px < 3; ++px) {
                            const int e = dx + px;           // 0..4, static
                            const float cv = (e < 4) ? f[e] : f4;
                            accH[px]    = fmaf(cv, w[k],      accH[px]);
                            accR[0][px] = fmaf(cv, w[9 + k],  accR[0][px]);
                            accR[1][px] = fmaf(cv, w[18 + k], accR[1][px]);
                            accR[2][px] = fmaf(cv, w[27 + k], accR[2][px]);
                            accR[3][px] = fmaf(cv, w[36 + k], accR[3][px]);
                        }
                    }
                }
            }
        }

        // ---- write prefetched z to the other zs buffer (late, post-head) ----
        if (tid < cnt) {
            int ch = tid / 49, q = tid - ch * 49;
            int u = q / 7, v = q - u * 7;
            zs[(gi + 1) & 1][ch * ZCH + u * 8 + v] = zr0;
        }
        if (tid + 256 < cnt) {
            int q2 = tid + 256;
            int ch = q2 / 49, q = q2 - ch * 49;
            int u = q / 7, v = q - u * 7;
            zs[(gi + 1) & 1][ch * ZCH + u * 8 + v] = zr1;
        }

        __syncthreads();   // B: cs free for overwrite; next zs buffer ready
    }

    // ---- epilogue: atomic accumulate (bias pre-written by init kernel) ----
    if (!hasS) return;
    const int p = sy * WO + cx;
    const bool full = (sx < 7);          // last strip in row has only 2 pixels

    float* outH = out + n * NPIX + p;
    float* outR = out + HEAT_SZ + (size_t)n * 4 * NPIX + p;
    atomicAdd(&outH[0], accH[0]);
    atomicAdd(&outH[1], accH[1]);
    if (full) atomicAdd(&outH[2], accH[2]);
    #pragma unroll
    for (int o = 0; o < 4; ++o) {
        float* pr = outR + o * NPIX;
        atomicAdd(&pr[0], accR[o][0]);
        atomicAdd(&pr[1], accR[o][1]);
        if (full) atomicAdd(&pr[2], accR[o][2]);
    }
}

extern "C" void kernel_launch(void* const* d_in, const int* in_sizes, int n_in,
                              void* d_out, int out_size, void* d_ws, size_t ws_size,
                              hipStream_t stream) {
    const float* x_f    = (const float*)d_in[0];
    const float* z_f    = (const float*)d_in[1];
    const float* heat_w = (const float*)d_in[2];
    const float* heat_b = (const float*)d_in[3];
    const float* reg_w  = (const float*)d_in[4];
    const float* reg_b  = (const float*)d_in[5];
    float* out = (float*)d_out;

    init_out_kernel<<<(OUT_TOTAL + 255) / 256, 256, 0, stream>>>(out, heat_b, reg_b);
    fused_head_kernel<<<NB * CHUNKS, 256, 0, stream>>>(x_f, z_f, heat_w, reg_w, out);
}